// Round 3
// baseline (185.356 us; speedup 1.0000x reference)
//
#include <hip/hip_runtime.h>

// Problem constants (from reference)
#define T_TREES 200
#define BATCH   2048
#define D_FEAT  512
#define N_NODE  64
#define LR      0.01f

typedef __attribute__((__ext_vector_type__(8)))  __bf16 bf16x8;
typedef __attribute__((__ext_vector_type__(16))) float  f32x16;

__device__ __forceinline__ unsigned short f32_to_bf16(float f) {
    unsigned u = __float_as_uint(f);
    u += 0x7FFFu + ((u >> 16) & 1u);   // RNE
    return (unsigned short)(u >> 16);
}

__device__ __forceinline__ void gload_lds16(const void* g, void* l) {
    __builtin_amdgcn_global_load_lds(
        (__attribute__((address_space(1))) void*)(void*)g,
        (__attribute__((address_space(3))) void*)l,
        16, 0, 0);
}

// ---------------- prep kernels ----------------

// x [2048][512] f32 -> bf16 (same layout)
__global__ void prep_x(const float* __restrict__ x, unsigned short* __restrict__ xb) {
    int i = blockIdx.x * 256 + threadIdx.x;           // 262144 float4 groups
    float4 v = ((const float4*)x)[i];
    ushort4 o;
    o.x = f32_to_bf16(v.x); o.y = f32_to_bf16(v.y);
    o.z = f32_to_bf16(v.z); o.w = f32_to_bf16(v.w);
    ((ushort4*)xb)[i] = o;
}

// w_t [t][d][n] f32 -> w_bt [t][n][d] bf16, transposed through LDS (coalesced both sides).
__global__ __launch_bounds__(256) void prep_wt(const float* __restrict__ w_t,
                                               unsigned short* __restrict__ w_bt) {
    __shared__ float tile[64 * 65];
    int t = blockIdx.x >> 3, slab = blockIdx.x & 7;
    const float* src = w_t + t * (D_FEAT * N_NODE) + slab * 4096;   // [64 d][64 n]
    #pragma unroll
    for (int p = 0; p < 16; ++p) {
        int idx = p * 256 + threadIdx.x;              // coalesced read
        tile[(idx >> 6) * 65 + (idx & 63)] = src[idx];
    }
    __syncthreads();
    unsigned short* dst = w_bt + t * (N_NODE * D_FEAT) + slab * 64; // row n stride 512
    #pragma unroll
    for (int p = 0; p < 8; ++p) {
        int idx = p * 256 + threadIdx.x;
        int n = idx >> 5, d = (idx & 31) * 2;
        ushort2 o;
        o.x = f32_to_bf16(tile[d * 65 + n]);
        o.y = f32_to_bf16(tile[(d + 1) * 65 + n]);
        *(ushort2*)(dst + n * D_FEAT + d) = o;        // coalesced 4B stores
    }
}

// w_d [t][n][15] f32 -> w_dt32 [t][32][64] bf16 (transposed, rows 15..31 zero)
__global__ void prep_wd(const float* __restrict__ w_d, unsigned short* __restrict__ w_dt) {
    int i = blockIdx.x * 256 + threadIdx.x;           // 409600 = 200*32*64
    int n = i & 63;
    int l = (i >> 6) & 31;
    int t = i >> 11;
    float v = (l < 15) ? w_d[(t * 64 + n) * 15 + l] : 0.f;
    w_dt[i] = f32_to_bf16(v);
}

// ---------------- main fused kernel ----------------
// One block = 1 tree x 256 batch rows, 256 threads (4 waves). Grid 1600.
// B tile = w_bt[t] (64 n x 512 k bf16 = 64 KB) fully resident in LDS, staged ONCE
// via global_load_lds. K-loop is BARRIER-FREE: A fragments come straight from
// global (each wave's rows are exclusive; 16 B contiguous = exact mfma A layout),
// B fragments from resident LDS. mfma_f32_32x32x16_bf16 (2382 TF pipe).
// LDS B layout: cell(kg = k/8, n) at (kg*64+n)*16 B -> staging is dense lane-order,
// frag reads are 512 B-contiguous runs (bank-uniform).
__global__ __launch_bounds__(256) void gbdt_main(
    const unsigned short* __restrict__ x_bf,   // [2048][512] bf16
    const unsigned short* __restrict__ w_bt,   // [200][64][512] bf16
    const unsigned short* __restrict__ w_dt,   // [200][32][64] bf16
    const float* __restrict__ b_t,             // [200][64]
    const float* __restrict__ b_d,             // [200][15]
    const float* __restrict__ w_l,             // [200][16]
    const float* __restrict__ b_l,             // [200]
    float* __restrict__ f_ws)                  // [200][2048]
{
    // [0,65536): B tile. After GEMM1: H (256 x 72 bf16 = 36864 B) overlays [0,36864);
    // P (256 x 17 f32 = 17408 B) at [40960, 58368).
    __shared__ alignas(16) char smem[65536];
    unsigned short* Hlds = (unsigned short*)smem;
    float*          Plds = (float*)(smem + 40960);

    const int tid    = threadIdx.x;
    const int lane   = tid & 63;
    const int w      = tid >> 6;
    const int lane31 = lane & 31;
    const int kh     = lane >> 5;         // k-half for 32x32x16 fragments

    const int bid = blockIdx.x;
    const int t   = bid >> 3;             // tree
    const int m0  = (bid & 7) << 8;       // batch-row tile * 256

    // ---- stage B once: 64 issues of 1 KB, 16 per wave ----
    {
        const unsigned short* src = w_bt + (t * 64 + lane) * D_FEAT;  // row n = lane
        #pragma unroll
        for (int i = 0; i < 16; ++i) {
            int kg = w * 16 + i;
            gload_lds16(src + kg * 8, smem + (kg * 64 + lane) * 16);
        }
    }

    // A fragment base pointers (per-wave-exclusive rows)
    const unsigned short* pA0 = x_bf + (m0 + w * 64 + lane31) * D_FEAT + kh * 8;
    const unsigned short* pA1 = pA0 + 32 * D_FEAT;
    // B fragment LDS byte offsets
    const char* pB0 = smem + (kh * 64 + lane31) * 16;
    const char* pB1 = pB0 + 32 * 16;

    f32x16 acc[2][2];
    #pragma unroll
    for (int mb = 0; mb < 2; ++mb)
        #pragma unroll
        for (int nb = 0; nb < 2; ++nb)
            acc[mb][nb] = (f32x16)(0.f);

    __syncthreads();                       // B resident (vmcnt(0) drained at barrier)

    // ---- barrier-free K loop: 32 chunks of k=16 ----
    bf16x8 a0 = *(const bf16x8*)(pA0);
    bf16x8 a1 = *(const bf16x8*)(pA1);
    bf16x8 b0 = *(const bf16x8*)(pB0);
    bf16x8 b1 = *(const bf16x8*)(pB1);
    #pragma unroll 4
    for (int kc = 0; kc < 32; ++kc) {
        bf16x8 na0, na1, nb0, nb1;
        if (kc < 31) {
            na0 = *(const bf16x8*)(pA0 + (kc + 1) * 16);
            na1 = *(const bf16x8*)(pA1 + (kc + 1) * 16);
            nb0 = *(const bf16x8*)(pB0 + (kc + 1) * 2048);
            nb1 = *(const bf16x8*)(pB1 + (kc + 1) * 2048);
        }
        acc[0][0] = __builtin_amdgcn_mfma_f32_32x32x16_bf16(a0, b0, acc[0][0], 0, 0, 0);
        acc[0][1] = __builtin_amdgcn_mfma_f32_32x32x16_bf16(a0, b1, acc[0][1], 0, 0, 0);
        acc[1][0] = __builtin_amdgcn_mfma_f32_32x32x16_bf16(a1, b0, acc[1][0], 0, 0, 0);
        acc[1][1] = __builtin_amdgcn_mfma_f32_32x32x16_bf16(a1, b1, acc[1][1], 0, 0, 0);
        a0 = na0; a1 = na1; b0 = nb0; b1 = nb1;
    }

    __syncthreads();                       // all B reads done; B region reusable for H

    // ---- epilogue: h = relu(acc + b_t) -> H LDS (row-major, stride 72, bf16) ----
    // C/D layout (m74/m101): col = lane&31, row = (r&3) + 8*(r>>2) + 4*(lane>>5)
    float btv[2];
    #pragma unroll
    for (int nb = 0; nb < 2; ++nb) btv[nb] = b_t[t * 64 + nb * 32 + lane31];
    #pragma unroll
    for (int mb = 0; mb < 2; ++mb)
        #pragma unroll
        for (int r = 0; r < 16; ++r) {
            int m = w * 64 + mb * 32 + (r & 3) + 8 * (r >> 2) + 4 * kh;
            #pragma unroll
            for (int nb = 0; nb < 2; ++nb) {
                float h = fmaxf(acc[mb][nb][r] + btv[nb], 0.f);
                Hlds[m * 72 + nb * 32 + lane31] = f32_to_bf16(h);
            }
        }
    __syncthreads();

    // ---- GEMM2: p_logit[256,16(of 32)] = h @ w_dt^T, K=64, B frags direct global ----
    f32x16 acc2[2] = { (f32x16)(0.f), (f32x16)(0.f) };
    const unsigned short* pW = w_dt + t * 2048 + lane31 * 64 + kh * 8;
    const int m_a2[2] = { w * 64 + lane31, w * 64 + 32 + lane31 };
    #pragma unroll
    for (int s = 0; s < 4; ++s) {
        bf16x8 bv = *(const bf16x8*)(pW + s * 16);
        #pragma unroll
        for (int mb = 0; mb < 2; ++mb) {
            bf16x8 av = *(const bf16x8*)(Hlds + m_a2[mb] * 72 + s * 16 + kh * 8);
            acc2[mb] = __builtin_amdgcn_mfma_f32_32x32x16_bf16(av, bv, acc2[mb], 0, 0, 0);
        }
    }
    // p = sigmoid(logit + b_d); only cols 0..14 are real decision nodes
    float bdv = (lane31 < 15) ? b_d[t * 15 + lane31] : 0.f;
    if (lane31 < 15) {
        #pragma unroll
        for (int mb = 0; mb < 2; ++mb)
            #pragma unroll
            for (int r = 0; r < 16; ++r) {
                int m = w * 64 + mb * 32 + (r & 3) + 8 * (r >> 2) + 4 * kh;
                float lg = acc2[mb][r] + bdv;
                Plds[m * 17 + lane31] = 1.f / (1.f + __expf(-lg));
            }
    }
    __syncthreads();

    // ---- soft routing mu + leaf score f = tanh(mu . w_l + b_l), thread = row ----
    {
        int m = tid;
        float pv[15];
        #pragma unroll
        for (int i = 0; i < 15; ++i) pv[i] = Plds[m * 17 + i];
        float facc = 0.f;
        #pragma unroll
        for (int leaf = 0; leaf < 16; ++leaf) {
            float mu = 1.f;
            int node = 0;
            #pragma unroll
            for (int d = 0; d < 4; ++d) {
                int bit = (leaf >> (3 - d)) & 1;
                float p = pv[node];
                mu *= bit ? (1.f - p) : p;
                node = 2 * node + 1 + bit;
            }
            facc += mu * w_l[t * 16 + leaf];
        }
        f_ws[t * BATCH + m0 + m] = tanhf(facc + b_l[t]);
    }
}

// ---------------- boosting prefix-sum ----------------
__global__ void scan_k(const float* __restrict__ f_ws, const float* __restrict__ f0p,
                       float* __restrict__ out) {
    int b = blockIdx.x, tid = threadIdx.x;
    int lane = tid & 63, wid = tid >> 6;
    float f0 = f0p[0];
    float x = (tid < T_TREES) ? f_ws[tid * BATCH + b] : 0.f;
    #pragma unroll
    for (int off = 1; off < 64; off <<= 1) {
        float y = __shfl_up(x, off, 64);
        if (lane >= off) x += y;
    }
    __shared__ float wsum[4];
    if (lane == 63) wsum[wid] = x;
    __syncthreads();
    float base = 0.f;
    for (int i = 0; i < wid; ++i) base += wsum[i];
    float incl = x + base;
    if (tid == 0) out[b * (T_TREES + 1)] = f0;
    if (tid < T_TREES) out[b * (T_TREES + 1) + 1 + tid] = f0 + LR * incl;
}

extern "C" void kernel_launch(void* const* d_in, const int* in_sizes, int n_in,
                              void* d_out, int out_size, void* d_ws, size_t ws_size,
                              hipStream_t stream) {
    const float* x   = (const float*)d_in[0];
    const float* w_t = (const float*)d_in[2];
    const float* b_t = (const float*)d_in[3];
    const float* w_d = (const float*)d_in[4];
    const float* b_d = (const float*)d_in[5];
    const float* w_l = (const float*)d_in[6];
    const float* b_l = (const float*)d_in[7];
    const float* f_0 = (const float*)d_in[8];
    float* out = (float*)d_out;

    char* ws = (char*)d_ws;
    unsigned short* x_bf = (unsigned short*)(ws);               // 2,097,152 B
    unsigned short* w_bt = (unsigned short*)(ws + 2097152);     // 13,107,200 B
    unsigned short* w_dt = (unsigned short*)(ws + 15204352);    //   819,200 B
    float*          f_ws = (float*)(ws + 16023552);             // 1,638,400 B

    prep_x  <<<1024, 256, 0, stream>>>(x, x_bf);
    prep_wt <<<1600, 256, 0, stream>>>(w_t, w_bt);
    prep_wd <<<1600, 256, 0, stream>>>(w_d, w_dt);
    gbdt_main<<<T_TREES * (BATCH / 256), 256, 0, stream>>>(
        x_bf, w_bt, w_dt, b_t, b_d, w_l, b_l, f_ws);
    scan_k<<<BATCH, 256, 0, stream>>>(f_ws, f_0, out);
}

// Round 4
// 182.011 us; speedup vs baseline: 1.0184x; 1.0184x over previous
//
#include <hip/hip_runtime.h>

// Problem constants (from reference)
#define T_TREES 200
#define BATCH   2048
#define D_FEAT  512
#define N_NODE  64
#define LR      0.01f

typedef __attribute__((__ext_vector_type__(8)))  __bf16 bf16x8;
typedef __attribute__((__ext_vector_type__(16))) float  f32x16;

__device__ __forceinline__ unsigned short f32_to_bf16(float f) {
    unsigned u = __float_as_uint(f);
    u += 0x7FFFu + ((u >> 16) & 1u);   // RNE
    return (unsigned short)(u >> 16);
}

__device__ __forceinline__ void gload_lds16(const void* g, void* l) {
    __builtin_amdgcn_global_load_lds(
        (__attribute__((address_space(1))) void*)(void*)g,
        (__attribute__((address_space(3))) void*)l,
        16, 0, 0);
}

// ---------------- prep kernels ----------------
// All outputs are k-group-major so the main kernel's staging is contiguous:
// x_p[mt 8][kg 64][m 256][8k] bf16 ; w_p[pair 100][kg 64][n' 128][8k] bf16.

// x [2048][512] f32 -> x_p. Block = 64-row x 64-k tile, transpose via LDS.
__global__ __launch_bounds__(256) void prep_x(const float* __restrict__ x,
                                              unsigned short* __restrict__ x_p) {
    __shared__ float tile[64 * 65];
    int mb = blockIdx.x >> 3;      // 64-row tile index (0..31)
    int slab = blockIdx.x & 7;     // 64-k slab (0..7)
    const float* src = x + (mb * 64) * D_FEAT + slab * 64;
    #pragma unroll
    for (int p = 0; p < 16; ++p) {
        int idx = p * 256 + threadIdx.x;
        int r = idx >> 6, c = idx & 63;
        tile[r * 65 + c] = src[r * D_FEAT + c];          // coalesced read
    }
    __syncthreads();
    int mt = mb >> 2, mq = mb & 3;
    unsigned short* dst = x_p + mt * 131072 + slab * 8 * 2048 + mq * 64 * 8;
    #pragma unroll
    for (int p = 0; p < 8; ++p) {
        int idx = p * 256 + threadIdx.x;                 // 0..2047
        int kgl = idx >> 8;                              // == p
        int r   = (idx >> 2) & 63;
        int jp  = idx & 3;
        ushort2 o;
        o.x = f32_to_bf16(tile[r * 65 + kgl * 8 + jp * 2]);
        o.y = f32_to_bf16(tile[r * 65 + kgl * 8 + jp * 2 + 1]);
        *(ushort2*)(dst + kgl * 2048 + r * 8 + jp * 2) = o;  // coalesced write
    }
}

// w_t [t][d][n] f32 -> w_p (pair-interleaved, kg-major). Block = (t, 64-d slab).
__global__ __launch_bounds__(256) void prep_wt(const float* __restrict__ w_t,
                                               unsigned short* __restrict__ w_p) {
    __shared__ float tile[64 * 65];
    int t = blockIdx.x >> 3, slab = blockIdx.x & 7;
    const float* src = w_t + t * (D_FEAT * N_NODE) + slab * 64 * N_NODE;  // [64 d][64 n]
    #pragma unroll
    for (int p = 0; p < 16; ++p) {
        int idx = p * 256 + threadIdx.x;
        int d = idx >> 6, n = idx & 63;
        tile[d * 65 + n] = src[d * N_NODE + n];          // coalesced read
    }
    __syncthreads();
    unsigned short* dst = w_p + (t >> 1) * 65536 + slab * 8 * 1024 + (t & 1) * 64 * 8;
    #pragma unroll
    for (int p = 0; p < 8; ++p) {
        int idx = p * 256 + threadIdx.x;
        int kgl = idx >> 8;
        int n   = (idx >> 2) & 63;
        int jp  = idx & 3;
        ushort2 o;
        o.x = f32_to_bf16(tile[(kgl * 8 + jp * 2) * 65 + n]);
        o.y = f32_to_bf16(tile[(kgl * 8 + jp * 2 + 1) * 65 + n]);
        *(ushort2*)(dst + kgl * 1024 + n * 8 + jp * 2) = o;  // coalesced write
    }
}

// w_d [t][n][15] f32 -> w_dt [t][32 node][64 n] bf16 (rows 15..31 zero)
__global__ void prep_wd(const float* __restrict__ w_d, unsigned short* __restrict__ w_dt) {
    int i = blockIdx.x * 256 + threadIdx.x;              // 409600 = 200*32*64
    int n = i & 63;
    int l = (i >> 6) & 31;
    int t = i >> 11;
    float v = (l < 15) ? w_d[(t * 64 + n) * 15 + l] : 0.f;
    w_dt[i] = f32_to_bf16(v);
}

// ---------------- main fused kernel ----------------
// Block = 2 trees (N=128) x 256 batch rows, 256 threads (4 waves), grid 800.
// Wave tile 128x64: wm = w>>1 row-half, wn = w&1 col-half (= tree).
// K-loop: 8 chunks of 64; staging A 32KB + B 16KB per chunk, every
// global_load_lds issue a contiguous 1KB run (kg-major prepped layouts);
// every ds_read_b128 a sequential conflict-free run. mfma_f32_32x32x16_bf16.
__global__ __launch_bounds__(256) void gbdt_main(
    const unsigned short* __restrict__ x_p,    // [8][64][256][8] bf16
    const unsigned short* __restrict__ w_p,    // [100][64][128][8] bf16
    const unsigned short* __restrict__ w_dt,   // [200][32][64] bf16
    const float* __restrict__ b_t,             // [200][64]
    const float* __restrict__ b_d,             // [200][15]
    const float* __restrict__ w_l,             // [200][16]
    const float* __restrict__ b_l,             // [200]
    float* __restrict__ f_ws)                  // [200][2048]
{
    // staging: A [0,32768) slot=(kg*256+m)*16 ; B [32768,49152) slot=(kg*128+n')*16
    // overlays after GEMM1: H [0,36864) 256 rows x 72 bf16 (144 B stride, 16B-aligned)
    //                       P [0,34816) 2 trees x 256 x 17 f32 (after GEMM2 done)
    __shared__ alignas(16) char smem[49152];
    unsigned short* H  = (unsigned short*)smem;
    float*          Pf = (float*)smem;

    const int tid    = threadIdx.x;
    const int lane   = tid & 63;
    const int w      = tid >> 6;
    const int lane31 = lane & 31;
    const int kh     = lane >> 5;
    const int wm     = w >> 1;       // row-half (0/1)
    const int wn     = w & 1;        // col-half = tree-in-pair (0/1)

    const int bid  = blockIdx.x;
    const int pair = bid >> 3;       // 0..99
    const int mt   = bid & 7;        // 256-row tile
    const int t0   = pair * 2;
    const int m0   = mt * 256;

    const unsigned short* gA = x_p + mt * 131072;    // + c*16384 + slot*8
    const unsigned short* gB = w_p + pair * 65536;   // + c*8192  + slot*8
    const int aslot = w * 512 + lane;                // + i*64, i<8
    const int bslot = w * 256 + lane;                // + i*64, i<4

    f32x16 acc[4][2];
    #pragma unroll
    for (int mb = 0; mb < 4; ++mb)
        #pragma unroll
        for (int nb = 0; nb < 2; ++nb)
            acc[mb][nb] = (f32x16)(0.f);

    // ---- K loop: 8 chunks of 64 ----
    for (int c = 0; c < 8; ++c) {
        __syncthreads();                             // previous chunk's reads done
        #pragma unroll
        for (int i = 0; i < 8; ++i) {
            int s = aslot + i * 64;
            gload_lds16(gA + c * 16384 + s * 8, smem + s * 16);
        }
        #pragma unroll
        for (int i = 0; i < 4; ++i) {
            int s = bslot + i * 64;
            gload_lds16(gB + c * 8192 + s * 8, smem + 32768 + s * 16);
        }
        __syncthreads();                             // staging drained
        #pragma unroll
        for (int s = 0; s < 4; ++s) {
            int kg2 = 2 * s + kh;
            bf16x8 av[4], bv[2];
            #pragma unroll
            for (int mb = 0; mb < 4; ++mb)
                av[mb] = *(const bf16x8*)(smem + (kg2 * 256 + wm * 128 + mb * 32 + lane31) * 16);
            #pragma unroll
            for (int nb = 0; nb < 2; ++nb)
                bv[nb] = *(const bf16x8*)(smem + 32768 + (kg2 * 128 + wn * 64 + nb * 32 + lane31) * 16);
            #pragma unroll
            for (int mb = 0; mb < 4; ++mb)
                #pragma unroll
                for (int nb = 0; nb < 2; ++nb)
                    acc[mb][nb] = __builtin_amdgcn_mfma_f32_32x32x16_bf16(
                        av[mb], bv[nb], acc[mb][nb], 0, 0, 0);
        }
    }

    __syncthreads();                                 // all GEMM1 frag reads done

    // ---- per-tree rounds: h -> H LDS -> GEMM2 ----
    // C/D layout (32x32): col = lane&31, row = (r&3) + 8*(r>>2) + 4*(lane>>5)
    float btv[2];
    #pragma unroll
    for (int nb = 0; nb < 2; ++nb)
        btv[nb] = b_t[(t0 + wn) * 64 + nb * 32 + lane31];

    f32x16 acc2[2][2];
    #pragma unroll
    for (int j = 0; j < 2; ++j) {
        if (wn == j) {                               // this wave holds tree j's h
            #pragma unroll
            for (int mb = 0; mb < 4; ++mb)
                #pragma unroll
                for (int nb = 0; nb < 2; ++nb)
                    #pragma unroll
                    for (int r = 0; r < 16; ++r) {
                        int m  = wm * 128 + mb * 32 + (r & 3) + 8 * (r >> 2) + 4 * kh;
                        int cl = nb * 32 + lane31;
                        float h = fmaxf(acc[mb][nb][r] + btv[nb], 0.f);
                        H[m * 72 + cl] = f32_to_bf16(h);
                    }
        }
        __syncthreads();                             // H_j visible
        #pragma unroll
        for (int i = 0; i < 2; ++i) acc2[j][i] = (f32x16)(0.f);
        const unsigned short* pW = w_dt + (t0 + j) * 2048 + lane31 * 64;
        #pragma unroll
        for (int s = 0; s < 4; ++s) {
            int kg2 = 2 * s + kh;
            bf16x8 bv = *(const bf16x8*)(pW + kg2 * 8);
            #pragma unroll
            for (int i = 0; i < 2; ++i) {
                int mrow = (w * 2 + i) * 32 + lane31;
                bf16x8 av = *(const bf16x8*)(H + mrow * 72 + kg2 * 8);
                acc2[j][i] = __builtin_amdgcn_mfma_f32_32x32x16_bf16(av, bv, acc2[j][i], 0, 0, 0);
            }
        }
        __syncthreads();                             // GEMM2_j reads done (H reusable)
    }

    // ---- p = sigmoid(logit + b_d) -> P [2][256][17] f32 (overlays H) ----
    float bdv[2];
    #pragma unroll
    for (int j = 0; j < 2; ++j)
        bdv[j] = (lane31 < 15) ? b_d[(t0 + j) * 15 + lane31] : 0.f;
    if (lane31 < 15) {
        #pragma unroll
        for (int j = 0; j < 2; ++j)
            #pragma unroll
            for (int i = 0; i < 2; ++i)
                #pragma unroll
                for (int r = 0; r < 16; ++r) {
                    int m = (w * 2 + i) * 32 + (r & 3) + 8 * (r >> 2) + 4 * kh;
                    float lg = acc2[j][i][r] + bdv[j];
                    Pf[(j * 256 + m) * 17 + lane31] = 1.f / (1.f + __expf(-lg));
                }
    }
    __syncthreads();

    // ---- soft routing + leaf score, thread = row, both trees ----
    {
        int m = tid;
        #pragma unroll
        for (int j = 0; j < 2; ++j) {
            int t = t0 + j;
            float pv[15];
            #pragma unroll
            for (int i = 0; i < 15; ++i) pv[i] = Pf[(j * 256 + m) * 17 + i];
            float facc = 0.f;
            #pragma unroll
            for (int leaf = 0; leaf < 16; ++leaf) {
                float mu = 1.f;
                int node = 0;
                #pragma unroll
                for (int d = 0; d < 4; ++d) {
                    int bit = (leaf >> (3 - d)) & 1;
                    float p = pv[node];
                    mu *= bit ? (1.f - p) : p;
                    node = 2 * node + 1 + bit;
                }
                facc += mu * w_l[t * 16 + leaf];
            }
            f_ws[t * BATCH + m0 + m] = tanhf(facc + b_l[t]);
        }
    }
}

// ---------------- boosting prefix-sum ----------------
__global__ void scan_k(const float* __restrict__ f_ws, const float* __restrict__ f0p,
                       float* __restrict__ out) {
    int b = blockIdx.x, tid = threadIdx.x;
    int lane = tid & 63, wid = tid >> 6;
    float f0 = f0p[0];
    float x = (tid < T_TREES) ? f_ws[tid * BATCH + b] : 0.f;
    #pragma unroll
    for (int off = 1; off < 64; off <<= 1) {
        float y = __shfl_up(x, off, 64);
        if (lane >= off) x += y;
    }
    __shared__ float wsum[4];
    if (lane == 63) wsum[wid] = x;
    __syncthreads();
    float base = 0.f;
    for (int i = 0; i < wid; ++i) base += wsum[i];
    float incl = x + base;
    if (tid == 0) out[b * (T_TREES + 1)] = f0;
    if (tid < T_TREES) out[b * (T_TREES + 1) + 1 + tid] = f0 + LR * incl;
}

extern "C" void kernel_launch(void* const* d_in, const int* in_sizes, int n_in,
                              void* d_out, int out_size, void* d_ws, size_t ws_size,
                              hipStream_t stream) {
    const float* x   = (const float*)d_in[0];
    const float* w_t = (const float*)d_in[2];
    const float* b_t = (const float*)d_in[3];
    const float* w_d = (const float*)d_in[4];
    const float* b_d = (const float*)d_in[5];
    const float* w_l = (const float*)d_in[6];
    const float* b_l = (const float*)d_in[7];
    const float* f_0 = (const float*)d_in[8];
    float* out = (float*)d_out;

    char* ws = (char*)d_ws;
    unsigned short* x_p  = (unsigned short*)(ws);               // 2,097,152 B
    unsigned short* w_p  = (unsigned short*)(ws + 2097152);     // 13,107,200 B
    unsigned short* w_dt = (unsigned short*)(ws + 15204352);    //   819,200 B
    float*          f_ws = (float*)(ws + 16023552);             // 1,638,400 B

    prep_x  <<< 256, 256, 0, stream>>>(x, x_p);
    prep_wt <<<1600, 256, 0, stream>>>(w_t, w_p);
    prep_wd <<<1600, 256, 0, stream>>>(w_d, w_dt);
    gbdt_main<<<800, 256, 0, stream>>>(x_p, w_p, w_dt, b_t, b_d, w_l, b_l, f_ws);
    scan_k<<<BATCH, 256, 0, stream>>>(f_ws, f_0, out);
}

// Round 5
// 157.386 us; speedup vs baseline: 1.1777x; 1.1565x over previous
//
#include <hip/hip_runtime.h>

// Problem constants (from reference)
#define T_TREES 200
#define BATCH   2048
#define D_FEAT  512
#define N_NODE  64
#define LR      0.01f

typedef __attribute__((__ext_vector_type__(8)))  __bf16 bf16x8;
typedef __attribute__((__ext_vector_type__(16))) float  f32x16;

__device__ __forceinline__ unsigned short f32_to_bf16(float f) {
    unsigned u = __float_as_uint(f);
    u += 0x7FFFu + ((u >> 16) & 1u);   // RNE
    return (unsigned short)(u >> 16);
}

__device__ __forceinline__ void gload_lds16(const void* g, void* l) {
    __builtin_amdgcn_global_load_lds(
        (__attribute__((address_space(1))) void*)(void*)g,
        (__attribute__((address_space(3))) void*)l,
        16, 0, 0);
}

// ---------------- prep kernels ----------------
// kg-major layouts so main-kernel staging is a dense linear copy:
// x_p[mt 8][kg 64][m 256][8k] bf16 ; w_p[pair 100][kg 64][n' 128][8k] bf16.

// x [2048][512] f32 -> x_p. Block = 64-row x 64-k tile, transpose via LDS.
__global__ __launch_bounds__(256) void prep_x(const float* __restrict__ x,
                                              unsigned short* __restrict__ x_p) {
    __shared__ float tile[64 * 65];
    int mb = blockIdx.x >> 3;      // 64-row tile index (0..31)
    int slab = blockIdx.x & 7;     // 64-k slab (0..7)
    const float* src = x + (mb * 64) * D_FEAT + slab * 64;
    #pragma unroll
    for (int p = 0; p < 16; ++p) {
        int idx = p * 256 + threadIdx.x;
        int r = idx >> 6, c = idx & 63;
        tile[r * 65 + c] = src[r * D_FEAT + c];          // coalesced read
    }
    __syncthreads();
    int mt = mb >> 2, mq = mb & 3;
    unsigned short* dst = x_p + mt * 131072 + slab * 8 * 2048 + mq * 64 * 8;
    #pragma unroll
    for (int p = 0; p < 8; ++p) {
        int idx = p * 256 + threadIdx.x;                 // 0..2047
        int kgl = idx >> 8;                              // == p
        int r   = (idx >> 2) & 63;
        int jp  = idx & 3;
        ushort2 o;
        o.x = f32_to_bf16(tile[r * 65 + kgl * 8 + jp * 2]);
        o.y = f32_to_bf16(tile[r * 65 + kgl * 8 + jp * 2 + 1]);
        *(ushort2*)(dst + kgl * 2048 + r * 8 + jp * 2) = o;  // coalesced write
    }
}

// w_t [t][d][n] f32 -> w_p (pair-interleaved, kg-major). Block = (t, 64-d slab).
__global__ __launch_bounds__(256) void prep_wt(const float* __restrict__ w_t,
                                               unsigned short* __restrict__ w_p) {
    __shared__ float tile[64 * 65];
    int t = blockIdx.x >> 3, slab = blockIdx.x & 7;
    const float* src = w_t + t * (D_FEAT * N_NODE) + slab * 64 * N_NODE;  // [64 d][64 n]
    #pragma unroll
    for (int p = 0; p < 16; ++p) {
        int idx = p * 256 + threadIdx.x;
        int d = idx >> 6, n = idx & 63;
        tile[d * 65 + n] = src[d * N_NODE + n];          // coalesced read
    }
    __syncthreads();
    unsigned short* dst = w_p + (t >> 1) * 65536 + slab * 8 * 1024 + (t & 1) * 64 * 8;
    #pragma unroll
    for (int p = 0; p < 8; ++p) {
        int idx = p * 256 + threadIdx.x;
        int kgl = idx >> 8;
        int n   = (idx >> 2) & 63;
        int jp  = idx & 3;
        ushort2 o;
        o.x = f32_to_bf16(tile[(kgl * 8 + jp * 2) * 65 + n]);
        o.y = f32_to_bf16(tile[(kgl * 8 + jp * 2 + 1) * 65 + n]);
        *(ushort2*)(dst + kgl * 1024 + n * 8 + jp * 2) = o;  // coalesced write
    }
}

// w_d [t][n][15] f32 -> w_dt [t][32 node][64 n] bf16 (rows 15..31 zero)
__global__ void prep_wd(const float* __restrict__ w_d, unsigned short* __restrict__ w_dt) {
    int i = blockIdx.x * 256 + threadIdx.x;              // 409600 = 200*32*64
    int n = i & 63;
    int l = (i >> 6) & 31;
    int t = i >> 11;
    float v = (l < 15) ? w_d[(t * 64 + n) * 15 + l] : 0.f;
    w_dt[i] = f32_to_bf16(v);
}

// ---------------- main fused kernel ----------------
// Block = 2 trees (N=128) x 256 batch rows, 256 threads (4 waves).
// Grid 832 (8 XCD x 13 pairs x 8 mtiles), 32 idle. Wave tile 128x64.
// K-loop: 16 chunks of BK=32, DOUBLE-BUFFERED (24 KB/buf): stage(c+1) issues
// before compute(c), so the vmcnt(0) drain at the barrier overlaps a full
// compute chunk. __launch_bounds__(256,3) caps VGPR at 170 -> 3 blocks/CU.
// Staging is a dense linear copy (kg-major prepped layouts); all ds_read_b128
// are 512B-contiguous runs (conflict-free).
__global__ __launch_bounds__(256, 3) void gbdt_main(
    const unsigned short* __restrict__ x_p,    // [8][64][256][8] bf16
    const unsigned short* __restrict__ w_p,    // [100][64][128][8] bf16
    const unsigned short* __restrict__ w_dt,   // [200][32][64] bf16
    const float* __restrict__ b_t,             // [200][64]
    const float* __restrict__ b_d,             // [200][15]
    const float* __restrict__ w_l,             // [200][16]
    const float* __restrict__ b_l,             // [200]
    float* __restrict__ f_ws)                  // [2048][200]  (b-major!)
{
    // dbuf: buf k at k*24576: A [0,16384) slot=(kgl*256+m)*16 ; B [16384,24576)
    // overlays after GEMM1: H [0,36864) 256 x 72 bf16 ; P [0,34816) [2][256][17] f32
    __shared__ alignas(16) char smem[49152];
    unsigned short* H  = (unsigned short*)smem;
    float*          Pf = (float*)smem;

    const int tid    = threadIdx.x;
    const int lane   = tid & 63;
    const int w      = tid >> 6;
    const int lane31 = lane & 31;
    const int kh     = lane >> 5;
    const int wm     = w >> 1;       // row-half (0/1)
    const int wn     = w & 1;        // col-half = tree-in-pair (0/1)

    // XCD swizzle: consecutive blockIdx -> XCDs round-robin (%8). Give each XCD
    // a private set of 13 pairs so w_p lands in one XCD's L2 only.
    const int xcd  = blockIdx.x & 7;
    const int slot = blockIdx.x >> 3;     // 0..103
    const int mt   = slot & 7;
    const int pj   = slot >> 3;           // 0..12
    const int pair = xcd * 13 + pj;
    if (pair >= 100) return;
    const int t0 = pair * 2;
    const int m0 = mt * 256;

    const char* pa = (const char*)(x_p + mt * 131072) + tid * 16;   // chunk stride 16384 B
    const char* pb = (const char*)(w_p + pair * 65536) + tid * 16;  // chunk stride 8192 B

    f32x16 acc[4][2];
    #pragma unroll
    for (int mb = 0; mb < 4; ++mb)
        #pragma unroll
        for (int nb = 0; nb < 2; ++nb)
            acc[mb][nb] = (f32x16)(0.f);

    // stage chunk 0 into buf 0
    #pragma unroll
    for (int i = 0; i < 4; ++i)
        gload_lds16(pa + i * 4096, smem + tid * 16 + i * 4096);
    #pragma unroll
    for (int i = 0; i < 2; ++i)
        gload_lds16(pb + i * 4096, smem + 16384 + tid * 16 + i * 4096);

    // ---- K loop: 16 chunks of 32, double-buffered, one barrier per chunk ----
    for (int c = 0; c < 16; ++c) {
        __syncthreads();                             // drains stage(c); prev reads done
        if (c < 15) {
            char* nb_ = smem + ((c + 1) & 1) * 24576;
            #pragma unroll
            for (int i = 0; i < 4; ++i)
                gload_lds16(pa + (c + 1) * 16384 + i * 4096, nb_ + tid * 16 + i * 4096);
            #pragma unroll
            for (int i = 0; i < 2; ++i)
                gload_lds16(pb + (c + 1) * 8192 + i * 4096, nb_ + 16384 + tid * 16 + i * 4096);
        }
        const char* bufA = smem + (c & 1) * 24576;
        const char* bufB = bufA + 16384;
        #pragma unroll
        for (int s2 = 0; s2 < 2; ++s2) {
            int kgl = 2 * s2 + kh;
            bf16x8 av[4], bv[2];
            #pragma unroll
            for (int mb = 0; mb < 4; ++mb)
                av[mb] = *(const bf16x8*)(bufA + (kgl * 256 + wm * 128 + mb * 32 + lane31) * 16);
            #pragma unroll
            for (int nb = 0; nb < 2; ++nb)
                bv[nb] = *(const bf16x8*)(bufB + (kgl * 128 + wn * 64 + nb * 32 + lane31) * 16);
            #pragma unroll
            for (int mb = 0; mb < 4; ++mb)
                #pragma unroll
                for (int nb = 0; nb < 2; ++nb)
                    acc[mb][nb] = __builtin_amdgcn_mfma_f32_32x32x16_bf16(
                        av[mb], bv[nb], acc[mb][nb], 0, 0, 0);
        }
    }

    __syncthreads();                                 // all GEMM1 frag reads done

    // ---- per-tree rounds: h -> H LDS -> GEMM2 ----
    // C/D layout (32x32): col = lane&31, row = (r&3) + 8*(r>>2) + 4*(lane>>5)
    float btv[2];
    #pragma unroll
    for (int nb = 0; nb < 2; ++nb)
        btv[nb] = b_t[(t0 + wn) * 64 + nb * 32 + lane31];

    f32x16 acc2[2][2];
    #pragma unroll
    for (int j = 0; j < 2; ++j) {
        if (wn == j) {                               // this wave holds tree j's h
            #pragma unroll
            for (int mb = 0; mb < 4; ++mb)
                #pragma unroll
                for (int nb = 0; nb < 2; ++nb)
                    #pragma unroll
                    for (int r = 0; r < 16; ++r) {
                        int m  = wm * 128 + mb * 32 + (r & 3) + 8 * (r >> 2) + 4 * kh;
                        int cl = nb * 32 + lane31;
                        float h = fmaxf(acc[mb][nb][r] + btv[nb], 0.f);
                        H[m * 72 + cl] = f32_to_bf16(h);
                    }
        }
        __syncthreads();                             // H_j visible
        #pragma unroll
        for (int i = 0; i < 2; ++i) acc2[j][i] = (f32x16)(0.f);
        const unsigned short* pW = w_dt + (t0 + j) * 2048 + lane31 * 64;
        #pragma unroll
        for (int s2 = 0; s2 < 4; ++s2) {
            int kg2 = 2 * s2 + kh;
            bf16x8 bv = *(const bf16x8*)(pW + kg2 * 8);
            #pragma unroll
            for (int i = 0; i < 2; ++i) {
                int mrow = (w * 2 + i) * 32 + lane31;
                bf16x8 av = *(const bf16x8*)(H + mrow * 72 + kg2 * 8);
                acc2[j][i] = __builtin_amdgcn_mfma_f32_32x32x16_bf16(av, bv, acc2[j][i], 0, 0, 0);
            }
        }
        __syncthreads();                             // GEMM2_j reads done (H reusable)
    }

    // ---- p = sigmoid(logit + b_d) -> P [2][256][17] f32 (overlays H) ----
    float bdv[2];
    #pragma unroll
    for (int j = 0; j < 2; ++j)
        bdv[j] = (lane31 < 15) ? b_d[(t0 + j) * 15 + lane31] : 0.f;
    if (lane31 < 15) {
        #pragma unroll
        for (int j = 0; j < 2; ++j)
            #pragma unroll
            for (int i = 0; i < 2; ++i)
                #pragma unroll
                for (int r = 0; r < 16; ++r) {
                    int m = (w * 2 + i) * 32 + (r & 3) + 8 * (r >> 2) + 4 * kh;
                    float lg = acc2[j][i][r] + bdv[j];
                    Pf[(j * 256 + m) * 17 + lane31] = 1.f / (1.f + __expf(-lg));
                }
    }
    __syncthreads();

    // ---- soft routing + leaf score, thread = row, both trees ----
    {
        int m = tid;
        #pragma unroll
        for (int j = 0; j < 2; ++j) {
            int t = t0 + j;
            float pv[15];
            #pragma unroll
            for (int i = 0; i < 15; ++i) pv[i] = Pf[(j * 256 + m) * 17 + i];
            float facc = 0.f;
            #pragma unroll
            for (int leaf = 0; leaf < 16; ++leaf) {
                float mu = 1.f;
                int node = 0;
                #pragma unroll
                for (int d = 0; d < 4; ++d) {
                    int bit = (leaf >> (3 - d)) & 1;
                    float p = pv[node];
                    mu *= bit ? (1.f - p) : p;
                    node = 2 * node + 1 + bit;
                }
                facc += mu * w_l[t * 16 + leaf];
            }
            f_ws[(m0 + m) * T_TREES + t] = tanhf(facc + b_l[t]);   // b-major
        }
    }
}

// ---------------- boosting prefix-sum ----------------
// f_ws is [B][T] -> coalesced read (thread tid reads f_ws[b*200+tid]).
__global__ void scan_k(const float* __restrict__ f_ws, const float* __restrict__ f0p,
                       float* __restrict__ out) {
    int b = blockIdx.x, tid = threadIdx.x;
    int lane = tid & 63, wid = tid >> 6;
    float f0 = f0p[0];
    float x = (tid < T_TREES) ? f_ws[b * T_TREES + tid] : 0.f;
    #pragma unroll
    for (int off = 1; off < 64; off <<= 1) {
        float y = __shfl_up(x, off, 64);
        if (lane >= off) x += y;
    }
    __shared__ float wsum[4];
    if (lane == 63) wsum[wid] = x;
    __syncthreads();
    float base = 0.f;
    for (int i = 0; i < wid; ++i) base += wsum[i];
    float incl = x + base;
    if (tid == 0) out[b * (T_TREES + 1)] = f0;
    if (tid < T_TREES) out[b * (T_TREES + 1) + 1 + tid] = f0 + LR * incl;
}

extern "C" void kernel_launch(void* const* d_in, const int* in_sizes, int n_in,
                              void* d_out, int out_size, void* d_ws, size_t ws_size,
                              hipStream_t stream) {
    const float* x   = (const float*)d_in[0];
    const float* w_t = (const float*)d_in[2];
    const float* b_t = (const float*)d_in[3];
    const float* w_d = (const float*)d_in[4];
    const float* b_d = (const float*)d_in[5];
    const float* w_l = (const float*)d_in[6];
    const float* b_l = (const float*)d_in[7];
    const float* f_0 = (const float*)d_in[8];
    float* out = (float*)d_out;

    char* ws = (char*)d_ws;
    unsigned short* x_p  = (unsigned short*)(ws);               // 2,097,152 B
    unsigned short* w_p  = (unsigned short*)(ws + 2097152);     // 13,107,200 B
    unsigned short* w_dt = (unsigned short*)(ws + 15204352);    //   819,200 B
    float*          f_ws = (float*)(ws + 16023552);             // 1,638,400 B

    prep_x  <<< 256, 256, 0, stream>>>(x, x_p);
    prep_wt <<<1600, 256, 0, stream>>>(w_t, w_p);
    prep_wd <<<1600, 256, 0, stream>>>(w_d, w_dt);
    gbdt_main<<<832, 256, 0, stream>>>(x_p, w_p, w_dt, b_t, b_d, w_l, b_l, f_ws);
    scan_k<<<BATCH, 256, 0, stream>>>(f_ws, f_0, out);
}

// Round 6
// 141.908 us; speedup vs baseline: 1.3062x; 1.1091x over previous
//
#include <hip/hip_runtime.h>

// Problem constants (from reference)
#define T_TREES 200
#define BATCH   2048
#define D_FEAT  512
#define N_NODE  64
#define LR      0.01f

typedef __attribute__((__ext_vector_type__(8)))  __bf16 bf16x8;
typedef __attribute__((__ext_vector_type__(16))) float  f32x16;

__device__ __forceinline__ unsigned short f32_to_bf16(float f) {
    unsigned u = __float_as_uint(f);
    u += 0x7FFFu + ((u >> 16) & 1u);   // RNE
    return (unsigned short)(u >> 16);
}

__device__ __forceinline__ void gload_lds16(const void* g, void* l) {
    __builtin_amdgcn_global_load_lds(
        (__attribute__((address_space(1))) void*)(void*)g,
        (__attribute__((address_space(3))) void*)l,
        16, 0, 0);
}

// ---------------- prep kernels ----------------
// kg-major layouts so main-kernel staging is a dense linear copy:
// x_p[mt 8][kg 64][m 256][8k] bf16 ; w_p[pair 100][kg 64][n' 128][8k] bf16.

// x [2048][512] f32 -> x_p. Block = 64-row x 64-k tile, transpose via LDS.
__global__ __launch_bounds__(256) void prep_x(const float* __restrict__ x,
                                              unsigned short* __restrict__ x_p) {
    __shared__ float tile[64 * 65];
    int mb = blockIdx.x >> 3;      // 64-row tile index (0..31)
    int slab = blockIdx.x & 7;     // 64-k slab (0..7)
    const float* src = x + (mb * 64) * D_FEAT + slab * 64;
    #pragma unroll
    for (int p = 0; p < 16; ++p) {
        int idx = p * 256 + threadIdx.x;
        int r = idx >> 6, c = idx & 63;
        tile[r * 65 + c] = src[r * D_FEAT + c];          // coalesced read
    }
    __syncthreads();
    int mt = mb >> 2, mq = mb & 3;
    unsigned short* dst = x_p + mt * 131072 + slab * 8 * 2048 + mq * 64 * 8;
    #pragma unroll
    for (int p = 0; p < 8; ++p) {
        int idx = p * 256 + threadIdx.x;                 // 0..2047
        int kgl = idx >> 8;                              // == p
        int r   = (idx >> 2) & 63;
        int jp  = idx & 3;
        ushort2 o;
        o.x = f32_to_bf16(tile[r * 65 + kgl * 8 + jp * 2]);
        o.y = f32_to_bf16(tile[r * 65 + kgl * 8 + jp * 2 + 1]);
        *(ushort2*)(dst + kgl * 2048 + r * 8 + jp * 2) = o;  // coalesced write
    }
}

// w_t [t][d][n] f32 -> w_p (pair-interleaved, kg-major). Block = (t, 64-d slab).
__global__ __launch_bounds__(256) void prep_wt(const float* __restrict__ w_t,
                                               unsigned short* __restrict__ w_p) {
    __shared__ float tile[64 * 65];
    int t = blockIdx.x >> 3, slab = blockIdx.x & 7;
    const float* src = w_t + t * (D_FEAT * N_NODE) + slab * 64 * N_NODE;  // [64 d][64 n]
    #pragma unroll
    for (int p = 0; p < 16; ++p) {
        int idx = p * 256 + threadIdx.x;
        int d = idx >> 6, n = idx & 63;
        tile[d * 65 + n] = src[d * N_NODE + n];          // coalesced read
    }
    __syncthreads();
    unsigned short* dst = w_p + (t >> 1) * 65536 + slab * 8 * 1024 + (t & 1) * 64 * 8;
    #pragma unroll
    for (int p = 0; p < 8; ++p) {
        int idx = p * 256 + threadIdx.x;
        int kgl = idx >> 8;
        int n   = (idx >> 2) & 63;
        int jp  = idx & 3;
        ushort2 o;
        o.x = f32_to_bf16(tile[(kgl * 8 + jp * 2) * 65 + n]);
        o.y = f32_to_bf16(tile[(kgl * 8 + jp * 2 + 1) * 65 + n]);
        *(ushort2*)(dst + kgl * 1024 + n * 8 + jp * 2) = o;  // coalesced write
    }
}

// w_d [t][n][15] f32 -> w_dt [t][32 node][64 n] bf16 (rows 15..31 zero)
__global__ void prep_wd(const float* __restrict__ w_d, unsigned short* __restrict__ w_dt) {
    int i = blockIdx.x * 256 + threadIdx.x;              // 409600 = 200*32*64
    int n = i & 63;
    int l = (i >> 6) & 31;
    int t = i >> 11;
    float v = (l < 15) ? w_d[(t * 64 + n) * 15 + l] : 0.f;
    w_dt[i] = f32_to_bf16(v);
}

// ---------------- main fused kernel ----------------
// Block = 2 trees (N=128) x 256 batch rows, 256 threads (4 waves).
// Grid 832 (8 XCD x 13 pairs x 8 mtiles), 32 idle. Wave tile 128x64.
// K-loop: 16 chunks of BK=32, double-buffered (24 KB/buf).
// __launch_bounds__(256,2): unified budget 256 regs (acc=128 AGPR + ~100 arch)
// -> NO spills (R5's (256,3) forced arch VGPR to 84 and spilled in-loop:
//    WRITE_SIZE 24.5 MB of scratch traffic, ~5kcyc/chunk stall).
__global__ __launch_bounds__(256, 2) void gbdt_main(
    const unsigned short* __restrict__ x_p,    // [8][64][256][8] bf16
    const unsigned short* __restrict__ w_p,    // [100][64][128][8] bf16
    const unsigned short* __restrict__ w_dt,   // [200][32][64] bf16
    const float* __restrict__ b_t,             // [200][64]
    const float* __restrict__ b_d,             // [200][15]
    const float* __restrict__ w_l,             // [200][16]
    const float* __restrict__ b_l,             // [200]
    float* __restrict__ f_ws)                  // [2048][200]  (b-major)
{
    // dbuf: buf k at k*24576: A [0,16384) slot=(kgl*256+m)*16 ; B [16384,24576)
    // overlays after GEMM1: H [0,36864) 256 x 72 bf16 ; P [0,34816) [2][256][17] f32
    __shared__ alignas(16) char smem[49152];
    unsigned short* H  = (unsigned short*)smem;
    float*          Pf = (float*)smem;

    const int tid    = threadIdx.x;
    const int lane   = tid & 63;
    const int w      = tid >> 6;
    const int lane31 = lane & 31;
    const int kh     = lane >> 5;
    const int wm     = w >> 1;       // row-half (0/1)
    const int wn     = w & 1;        // col-half = tree-in-pair (0/1)

    // XCD swizzle: consecutive blockIdx -> XCDs round-robin (%8); each XCD gets
    // a private set of 13 pairs so w_p lands in one XCD's L2 only.
    const int xcd  = blockIdx.x & 7;
    const int slot = blockIdx.x >> 3;     // 0..103
    const int mt   = slot & 7;
    const int pj   = slot >> 3;           // 0..12
    const int pair = xcd * 13 + pj;
    if (pair >= 100) return;
    const int t0 = pair * 2;
    const int m0 = mt * 256;

    const char* pa = (const char*)(x_p + mt * 131072) + tid * 16;   // chunk stride 16384 B
    const char* pb = (const char*)(w_p + pair * 65536) + tid * 16;  // chunk stride 8192 B

    f32x16 acc[4][2];
    #pragma unroll
    for (int mb = 0; mb < 4; ++mb)
        #pragma unroll
        for (int nb = 0; nb < 2; ++nb)
            acc[mb][nb] = (f32x16)(0.f);

    // stage chunk 0 into buf 0
    #pragma unroll
    for (int i = 0; i < 4; ++i)
        gload_lds16(pa + i * 4096, smem + tid * 16 + i * 4096);
    #pragma unroll
    for (int i = 0; i < 2; ++i)
        gload_lds16(pb + i * 4096, smem + 16384 + tid * 16 + i * 4096);

    // precompute frag LDS byte offsets (loop-invariant)
    const int aoff = (wm * 128 + lane31) * 16;   // + kgl*4096 + mb*512
    const int boff = 16384 + (wn * 64 + lane31) * 16;  // + kgl*2048 + nb*512

    // ---- K loop: 16 chunks of 32, double-buffered, one barrier per chunk ----
    for (int c = 0; c < 16; ++c) {
        __syncthreads();                             // drains stage(c); prev reads done
        if (c < 15) {
            char* nx = smem + ((c + 1) & 1) * 24576;
            #pragma unroll
            for (int i = 0; i < 4; ++i)
                gload_lds16(pa + (c + 1) * 16384 + i * 4096, nx + tid * 16 + i * 4096);
            #pragma unroll
            for (int i = 0; i < 2; ++i)
                gload_lds16(pb + (c + 1) * 8192 + i * 4096, nx + 16384 + tid * 16 + i * 4096);
        }
        const char* buf = smem + (c & 1) * 24576;
        #pragma unroll
        for (int s2 = 0; s2 < 2; ++s2) {
            const int kgl = 2 * s2 + kh;
            bf16x8 av[4], bv[2];
            #pragma unroll
            for (int mb = 0; mb < 4; ++mb)
                av[mb] = *(const bf16x8*)(buf + aoff + kgl * 4096 + mb * 512);
            #pragma unroll
            for (int nb = 0; nb < 2; ++nb)
                bv[nb] = *(const bf16x8*)(buf + boff + kgl * 2048 + nb * 512);
            #pragma unroll
            for (int mb = 0; mb < 4; ++mb)
                #pragma unroll
                for (int nb = 0; nb < 2; ++nb)
                    acc[mb][nb] = __builtin_amdgcn_mfma_f32_32x32x16_bf16(
                        av[mb], bv[nb], acc[mb][nb], 0, 0, 0);
        }
    }

    __syncthreads();                                 // all GEMM1 frag reads done

    // ---- per-tree rounds: h -> H LDS -> GEMM2 ----
    // C/D layout (32x32): col = lane&31, row = (r&3) + 8*(r>>2) + 4*(lane>>5)
    float btv[2];
    #pragma unroll
    for (int nb = 0; nb < 2; ++nb)
        btv[nb] = b_t[(t0 + wn) * 64 + nb * 32 + lane31];

    f32x16 acc2[2][2];
    #pragma unroll
    for (int j = 0; j < 2; ++j) {
        if (wn == j) {                               // this wave holds tree j's h
            #pragma unroll
            for (int mb = 0; mb < 4; ++mb)
                #pragma unroll
                for (int nb = 0; nb < 2; ++nb)
                    #pragma unroll
                    for (int r = 0; r < 16; ++r) {
                        int m  = wm * 128 + mb * 32 + (r & 3) + 8 * (r >> 2) + 4 * kh;
                        int cl = nb * 32 + lane31;
                        float h = fmaxf(acc[mb][nb][r] + btv[nb], 0.f);
                        H[m * 72 + cl] = f32_to_bf16(h);
                    }
        }
        __syncthreads();                             // H_j visible
        #pragma unroll
        for (int i = 0; i < 2; ++i) acc2[j][i] = (f32x16)(0.f);
        const unsigned short* pW = w_dt + (t0 + j) * 2048 + lane31 * 64;
        #pragma unroll
        for (int s2 = 0; s2 < 4; ++s2) {
            int kg2 = 2 * s2 + kh;
            bf16x8 bv = *(const bf16x8*)(pW + kg2 * 8);
            #pragma unroll
            for (int i = 0; i < 2; ++i) {
                int mrow = (w * 2 + i) * 32 + lane31;
                bf16x8 av = *(const bf16x8*)(H + mrow * 72 + kg2 * 8);
                acc2[j][i] = __builtin_amdgcn_mfma_f32_32x32x16_bf16(av, bv, acc2[j][i], 0, 0, 0);
            }
        }
        __syncthreads();                             // GEMM2_j reads done (H reusable)
    }

    // ---- p = sigmoid(logit + b_d) -> P [2][256][17] f32 (overlays H) ----
    float bdv[2];
    #pragma unroll
    for (int j = 0; j < 2; ++j)
        bdv[j] = (lane31 < 15) ? b_d[(t0 + j) * 15 + lane31] : 0.f;
    if (lane31 < 15) {
        #pragma unroll
        for (int j = 0; j < 2; ++j)
            #pragma unroll
            for (int i = 0; i < 2; ++i)
                #pragma unroll
                for (int r = 0; r < 16; ++r) {
                    int m = (w * 2 + i) * 32 + (r & 3) + 8 * (r >> 2) + 4 * kh;
                    float lg = acc2[j][i][r] + bdv[j];
                    Pf[(j * 256 + m) * 17 + lane31] = 1.f / (1.f + __expf(-lg));
                }
    }
    __syncthreads();

    // ---- soft routing + leaf score, thread = row, both trees ----
    {
        int m = tid;
        #pragma unroll
        for (int j = 0; j < 2; ++j) {
            int t = t0 + j;
            float pv[15];
            #pragma unroll
            for (int i = 0; i < 15; ++i) pv[i] = Pf[(j * 256 + m) * 17 + i];
            float facc = 0.f;
            #pragma unroll
            for (int leaf = 0; leaf < 16; ++leaf) {
                float mu = 1.f;
                int node = 0;
                #pragma unroll
                for (int d = 0; d < 4; ++d) {
                    int bit = (leaf >> (3 - d)) & 1;
                    float p = pv[node];
                    mu *= bit ? (1.f - p) : p;
                    node = 2 * node + 1 + bit;
                }
                facc += mu * w_l[t * 16 + leaf];
            }
            f_ws[(m0 + m) * T_TREES + t] = tanhf(facc + b_l[t]);   // b-major
        }
    }
}

// ---------------- boosting prefix-sum ----------------
// f_ws is [B][T] -> coalesced read (thread tid reads f_ws[b*200+tid]).
__global__ void scan_k(const float* __restrict__ f_ws, const float* __restrict__ f0p,
                       float* __restrict__ out) {
    int b = blockIdx.x, tid = threadIdx.x;
    int lane = tid & 63, wid = tid >> 6;
    float f0 = f0p[0];
    float x = (tid < T_TREES) ? f_ws[b * T_TREES + tid] : 0.f;
    #pragma unroll
    for (int off = 1; off < 64; off <<= 1) {
        float y = __shfl_up(x, off, 64);
        if (lane >= off) x += y;
    }
    __shared__ float wsum[4];
    if (lane == 63) wsum[wid] = x;
    __syncthreads();
    float base = 0.f;
    for (int i = 0; i < wid; ++i) base += wsum[i];
    float incl = x + base;
    if (tid == 0) out[b * (T_TREES + 1)] = f0;
    if (tid < T_TREES) out[b * (T_TREES + 1) + 1 + tid] = f0 + LR * incl;
}

extern "C" void kernel_launch(void* const* d_in, const int* in_sizes, int n_in,
                              void* d_out, int out_size, void* d_ws, size_t ws_size,
                              hipStream_t stream) {
    const float* x   = (const float*)d_in[0];
    const float* w_t = (const float*)d_in[2];
    const float* b_t = (const float*)d_in[3];
    const float* w_d = (const float*)d_in[4];
    const float* b_d = (const float*)d_in[5];
    const float* w_l = (const float*)d_in[6];
    const float* b_l = (const float*)d_in[7];
    const float* f_0 = (const float*)d_in[8];
    float* out = (float*)d_out;

    char* ws = (char*)d_ws;
    unsigned short* x_p  = (unsigned short*)(ws);               // 2,097,152 B
    unsigned short* w_p  = (unsigned short*)(ws + 2097152);     // 13,107,200 B
    unsigned short* w_dt = (unsigned short*)(ws + 15204352);    //   819,200 B
    float*          f_ws = (float*)(ws + 16023552);             // 1,638,400 B

    prep_x  <<< 256, 256, 0, stream>>>(x, x_p);
    prep_wt <<<1600, 256, 0, stream>>>(w_t, w_p);
    prep_wd <<<1600, 256, 0, stream>>>(w_d, w_dt);
    gbdt_main<<<832, 256, 0, stream>>>(x_p, w_p, w_dt, b_t, b_d, w_l, b_l, f_ws);
    scan_k<<<BATCH, 256, 0, stream>>>(f_ws, f_0, out);
}

// Round 7
// 134.130 us; speedup vs baseline: 1.3819x; 1.0580x over previous
//
#include <hip/hip_runtime.h>

// Problem constants (from reference)
#define T_TREES 200
#define BATCH   2048
#define D_FEAT  512
#define N_NODE  64
#define LR      0.01f

typedef __attribute__((__ext_vector_type__(8)))  __bf16 bf16x8;
typedef __attribute__((__ext_vector_type__(16))) float  f32x16;

__device__ __forceinline__ unsigned short f32_to_bf16(float f) {
    unsigned u = __float_as_uint(f);
    u += 0x7FFFu + ((u >> 16) & 1u);   // RNE
    return (unsigned short)(u >> 16);
}

__device__ __forceinline__ void gload_lds16(const void* g, void* l) {
    __builtin_amdgcn_global_load_lds(
        (__attribute__((address_space(1))) void*)(void*)g,
        (__attribute__((address_space(3))) void*)l,
        16, 0, 0);
}

// ---------------- prep kernels ----------------
// kg-major layouts so main-kernel staging is a dense linear copy:
// x_p[mt 16][kg 64][m 128][8k] bf16 ; w_p[pair 100][kg 64][n' 128][8k] bf16.

// x [2048][512] f32 -> x_p. Block = 64-row x 64-k tile, transpose via LDS.
__global__ __launch_bounds__(256) void prep_x(const float* __restrict__ x,
                                              unsigned short* __restrict__ x_p) {
    __shared__ float tile[64 * 65];
    int mb = blockIdx.x >> 3;      // 64-row tile index (0..31)
    int slab = blockIdx.x & 7;     // 64-k slab (0..7)
    const float* src = x + (mb * 64) * D_FEAT + slab * 64;
    #pragma unroll
    for (int p = 0; p < 16; ++p) {
        int idx = p * 256 + threadIdx.x;
        int r = idx >> 6, c = idx & 63;
        tile[r * 65 + c] = src[r * D_FEAT + c];          // coalesced read
    }
    __syncthreads();
    int mt = mb >> 1, mq = mb & 1;
    unsigned short* dst = x_p + mt * 65536 + slab * 8192 + mq * 512;
    #pragma unroll
    for (int p = 0; p < 8; ++p) {
        int idx = p * 256 + threadIdx.x;                 // 0..2047
        int kgl = idx >> 8;                              // == p
        int r   = (idx >> 2) & 63;
        int jp  = idx & 3;
        ushort2 o;
        o.x = f32_to_bf16(tile[r * 65 + kgl * 8 + jp * 2]);
        o.y = f32_to_bf16(tile[r * 65 + kgl * 8 + jp * 2 + 1]);
        *(ushort2*)(dst + kgl * 1024 + r * 8 + jp * 2) = o;  // coalesced write
    }
}

// w_t [t][d][n] f32 -> w_p (pair-interleaved, kg-major). Block = (t, 64-d slab).
__global__ __launch_bounds__(256) void prep_wt(const float* __restrict__ w_t,
                                               unsigned short* __restrict__ w_p) {
    __shared__ float tile[64 * 65];
    int t = blockIdx.x >> 3, slab = blockIdx.x & 7;
    const float* src = w_t + t * (D_FEAT * N_NODE) + slab * 64 * N_NODE;  // [64 d][64 n]
    #pragma unroll
    for (int p = 0; p < 16; ++p) {
        int idx = p * 256 + threadIdx.x;
        int d = idx >> 6, n = idx & 63;
        tile[d * 65 + n] = src[d * N_NODE + n];          // coalesced read
    }
    __syncthreads();
    unsigned short* dst = w_p + (t >> 1) * 65536 + slab * 8192 + (t & 1) * 512;
    #pragma unroll
    for (int p = 0; p < 8; ++p) {
        int idx = p * 256 + threadIdx.x;
        int kgl = idx >> 8;
        int n   = (idx >> 2) & 63;
        int jp  = idx & 3;
        ushort2 o;
        o.x = f32_to_bf16(tile[(kgl * 8 + jp * 2) * 65 + n]);
        o.y = f32_to_bf16(tile[(kgl * 8 + jp * 2 + 1) * 65 + n]);
        *(ushort2*)(dst + kgl * 1024 + n * 8 + jp * 2) = o;  // coalesced write
    }
}

// w_d [t][n][15] f32 -> w_dt [t][32 node][64 n] bf16 (rows 15..31 zero)
__global__ void prep_wd(const float* __restrict__ w_d, unsigned short* __restrict__ w_dt) {
    int i = blockIdx.x * 256 + threadIdx.x;              // 409600 = 200*32*64
    int n = i & 63;
    int l = (i >> 6) & 31;
    int t = i >> 11;
    float v = (l < 15) ? w_d[(t * 64 + n) * 15 + l] : 0.f;
    w_dt[i] = f32_to_bf16(v);
}

// ---------------- main fused kernel ----------------
// Block = 2 trees (N=128) x 128 batch rows, 256 threads (4 waves).
// Wave tile 64x64: wm = w>>1 row-half, wn = w&1 = tree. acc = 4 tiles = 64 AGPR
// -> total regs ~130 -> 3-4 blocks/CU (12-16 waves): deep inter-block overlap
// of barrier drains (R6 ran at 1 block/CU: acc+acc2 = 192 AGPR live together).
// Epilogue writes BOTH trees' H before GEMM2 so acc dies before acc2 is born.
// Grid 1664 = 8 XCD x 13 pairs x 16 mtiles (64 idle): w_p slice pinned per-XCD L2.
// K-loop: 16 chunks of BK=32, double-buffered (16 KB/buf), 4 gload16/thread/chunk.
__global__ __launch_bounds__(256, 3) void gbdt_main(
    const unsigned short* __restrict__ x_p,    // [16][64][128][8] bf16
    const unsigned short* __restrict__ w_p,    // [100][64][128][8] bf16
    const unsigned short* __restrict__ w_dt,   // [200][32][64] bf16
    const float* __restrict__ b_t,             // [200][64]
    const float* __restrict__ b_d,             // [200][15]
    const float* __restrict__ w_l,             // [200][16]
    const float* __restrict__ b_l,             // [200]
    float* __restrict__ f_ws)                  // [2048][200]  (b-major)
{
    // dbuf: buf k at k*16384: A [0,8192) (kg-major 128 rows), B [8192,16384).
    // overlays: H [0,34816) = [2 tree][128 m][68 col] bf16 (stride 136 B: 2-way
    // bank alias on GEMM2 frag reads = free); P [0,17408) = [2][128][17] f32.
    __shared__ alignas(16) char smem[36864];
    unsigned short* Hs = (unsigned short*)smem;
    float*          Pf = (float*)smem;

    const int tid    = threadIdx.x;
    const int lane   = tid & 63;
    const int w      = tid >> 6;
    const int lane31 = lane & 31;
    const int kh     = lane >> 5;
    const int wm     = w >> 1;       // row-half (0/1)
    const int wn     = w & 1;        // tree-in-pair (0/1)

    const int xcd  = blockIdx.x & 7;
    const int slot = blockIdx.x >> 3;     // 0..207
    const int mt   = slot & 15;           // 128-row tile
    const int pj   = slot >> 4;           // 0..12
    const int pair = xcd * 13 + pj;
    if (pair >= 100) return;
    const int t0 = pair * 2;
    const int m0 = mt * 128;

    const char* ga = (const char*)(x_p + mt * 65536) + tid * 16;    // chunk stride 8192 B
    const char* gb = (const char*)(w_p + pair * 65536) + tid * 16;  // chunk stride 8192 B

    f32x16 acc[2][2];
    #pragma unroll
    for (int mb = 0; mb < 2; ++mb)
        #pragma unroll
        for (int nb = 0; nb < 2; ++nb)
            acc[mb][nb] = (f32x16)(0.f);

    // stage chunk 0 into buf 0
    #pragma unroll
    for (int i = 0; i < 2; ++i) {
        gload_lds16(ga + i * 4096, smem + tid * 16 + i * 4096);
        gload_lds16(gb + i * 4096, smem + 8192 + tid * 16 + i * 4096);
    }

    const int aoff = (wm * 64 + lane31) * 16;          // + kgl*2048 + mb*512
    const int boff = 8192 + (wn * 64 + lane31) * 16;   // + kgl*2048 + nb*512

    // ---- K loop: 16 chunks of 32, double-buffered, one barrier per chunk ----
    for (int c = 0; c < 16; ++c) {
        __syncthreads();                             // drains stage(c); prev reads done
        if (c < 15) {
            char* nx = smem + ((c + 1) & 1) * 16384;
            #pragma unroll
            for (int i = 0; i < 2; ++i) {
                gload_lds16(ga + (c + 1) * 8192 + i * 4096, nx + tid * 16 + i * 4096);
                gload_lds16(gb + (c + 1) * 8192 + i * 4096, nx + 8192 + tid * 16 + i * 4096);
            }
        }
        const char* buf = smem + (c & 1) * 16384;
        #pragma unroll
        for (int s2 = 0; s2 < 2; ++s2) {
            const int kgl = 2 * s2 + kh;
            bf16x8 av[2], bv[2];
            #pragma unroll
            for (int mb = 0; mb < 2; ++mb)
                av[mb] = *(const bf16x8*)(buf + aoff + kgl * 2048 + mb * 512);
            #pragma unroll
            for (int nb = 0; nb < 2; ++nb)
                bv[nb] = *(const bf16x8*)(buf + boff + kgl * 2048 + nb * 512);
            #pragma unroll
            for (int mb = 0; mb < 2; ++mb)
                #pragma unroll
                for (int nb = 0; nb < 2; ++nb)
                    acc[mb][nb] = __builtin_amdgcn_mfma_f32_32x32x16_bf16(
                        av[mb], bv[nb], acc[mb][nb], 0, 0, 0);
        }
    }

    __syncthreads();                                 // all GEMM1 frag reads done

    // ---- epilogue: BOTH trees' h = relu(acc + b_t) -> H LDS; acc dies here ----
    // C/D layout (32x32): col = lane&31, row = (r&3) + 8*(r>>2) + 4*(lane>>5)
    #pragma unroll
    for (int nb = 0; nb < 2; ++nb) {
        float btv = b_t[(t0 + wn) * 64 + nb * 32 + lane31];
        #pragma unroll
        for (int mb = 0; mb < 2; ++mb)
            #pragma unroll
            for (int r = 0; r < 16; ++r) {
                int m = wm * 64 + mb * 32 + (r & 3) + 8 * (r >> 2) + 4 * kh;
                float h = fmaxf(acc[mb][nb][r] + btv, 0.f);
                Hs[wn * 8704 + m * 68 + nb * 32 + lane31] = f32_to_bf16(h);
            }
    }
    __syncthreads();                                 // H complete for both trees

    // ---- GEMM2: wave (wm,wn): logit[64 m x 16 l] for tree wn, K=64 ----
    f32x16 acc2[2] = { (f32x16)(0.f), (f32x16)(0.f) };
    const unsigned short* pW = w_dt + (t0 + wn) * 2048 + lane31 * 64 + kh * 8;
    #pragma unroll
    for (int s = 0; s < 4; ++s) {
        bf16x8 bv = *(const bf16x8*)(pW + s * 16);
        #pragma unroll
        for (int i = 0; i < 2; ++i) {
            const unsigned short* pH =
                Hs + wn * 8704 + (wm * 64 + i * 32 + lane31) * 68 + s * 16 + kh * 8;
            bf16x8 av = *(const bf16x8*)pH;
            acc2[i] = __builtin_amdgcn_mfma_f32_32x32x16_bf16(av, bv, acc2[i], 0, 0, 0);
        }
    }
    __syncthreads();                                 // H reads done (P overlays H)

    // ---- p = sigmoid(logit + b_d) -> P [2][128][17] f32 ----
    if (lane31 < 15) {
        float bdv = b_d[(t0 + wn) * 15 + lane31];
        #pragma unroll
        for (int i = 0; i < 2; ++i)
            #pragma unroll
            for (int r = 0; r < 16; ++r) {
                int m = wm * 64 + i * 32 + (r & 3) + 8 * (r >> 2) + 4 * kh;
                float lg = acc2[i][r] + bdv;
                Pf[(wn * 128 + m) * 17 + lane31] = 1.f / (1.f + __expf(-lg));
            }
    }
    __syncthreads();

    // ---- soft routing + leaf score: thread = (tree j, row m) ----
    {
        int m = tid & 127;
        int j = tid >> 7;
        int t = t0 + j;
        float pv[15];
        #pragma unroll
        for (int i = 0; i < 15; ++i) pv[i] = Pf[(j * 128 + m) * 17 + i];
        float facc = 0.f;
        #pragma unroll
        for (int leaf = 0; leaf < 16; ++leaf) {
            float mu = 1.f;
            int node = 0;
            #pragma unroll
            for (int d = 0; d < 4; ++d) {
                int bit = (leaf >> (3 - d)) & 1;
                float p = pv[node];
                mu *= bit ? (1.f - p) : p;
                node = 2 * node + 1 + bit;
            }
            facc += mu * w_l[t * 16 + leaf];
        }
        f_ws[(m0 + m) * T_TREES + t] = tanhf(facc + b_l[t]);   // b-major
    }
}

// ---------------- boosting prefix-sum ----------------
// f_ws is [B][T] -> coalesced read.
__global__ void scan_k(const float* __restrict__ f_ws, const float* __restrict__ f0p,
                       float* __restrict__ out) {
    int b = blockIdx.x, tid = threadIdx.x;
    int lane = tid & 63, wid = tid >> 6;
    float f0 = f0p[0];
    float x = (tid < T_TREES) ? f_ws[b * T_TREES + tid] : 0.f;
    #pragma unroll
    for (int off = 1; off < 64; off <<= 1) {
        float y = __shfl_up(x, off, 64);
        if (lane >= off) x += y;
    }
    __shared__ float wsum[4];
    if (lane == 63) wsum[wid] = x;
    __syncthreads();
    float base = 0.f;
    for (int i = 0; i < wid; ++i) base += wsum[i];
    float incl = x + base;
    if (tid == 0) out[b * (T_TREES + 1)] = f0;
    if (tid < T_TREES) out[b * (T_TREES + 1) + 1 + tid] = f0 + LR * incl;
}

extern "C" void kernel_launch(void* const* d_in, const int* in_sizes, int n_in,
                              void* d_out, int out_size, void* d_ws, size_t ws_size,
                              hipStream_t stream) {
    const float* x   = (const float*)d_in[0];
    const float* w_t = (const float*)d_in[2];
    const float* b_t = (const float*)d_in[3];
    const float* w_d = (const float*)d_in[4];
    const float* b_d = (const float*)d_in[5];
    const float* w_l = (const float*)d_in[6];
    const float* b_l = (const float*)d_in[7];
    const float* f_0 = (const float*)d_in[8];
    float* out = (float*)d_out;

    char* ws = (char*)d_ws;
    unsigned short* x_p  = (unsigned short*)(ws);               // 2,097,152 B
    unsigned short* w_p  = (unsigned short*)(ws + 2097152);     // 13,107,200 B
    unsigned short* w_dt = (unsigned short*)(ws + 15204352);    //   819,200 B
    float*          f_ws = (float*)(ws + 16023552);             // 1,638,400 B

    prep_x  <<< 256, 256, 0, stream>>>(x, x_p);
    prep_wt <<<1600, 256, 0, stream>>>(w_t, w_p);
    prep_wd <<<1600, 256, 0, stream>>>(w_d, w_dt);
    gbdt_main<<<1664, 256, 0, stream>>>(x_p, w_p, w_dt, b_t, b_d, w_l, b_l, f_ws);
    scan_k<<<BATCH, 256, 0, stream>>>(f_ws, f_0, out);
}

// Round 8
// 131.100 us; speedup vs baseline: 1.4139x; 1.0231x over previous
//
#include <hip/hip_runtime.h>

// Problem constants (from reference)
#define T_TREES 200
#define BATCH   2048
#define D_FEAT  512
#define N_NODE  64
#define LR      0.01f

typedef __attribute__((__ext_vector_type__(8)))  __bf16 bf16x8;
typedef __attribute__((__ext_vector_type__(16))) float  f32x16;

__device__ __forceinline__ unsigned short f32_to_bf16(float f) {
    unsigned u = __float_as_uint(f);
    u += 0x7FFFu + ((u >> 16) & 1u);   // RNE
    return (unsigned short)(u >> 16);
}

__device__ __forceinline__ void gload_lds16(const void* g, void* l) {
    __builtin_amdgcn_global_load_lds(
        (__attribute__((address_space(1))) void*)(void*)g,
        (__attribute__((address_space(3))) void*)l,
        16, 0, 0);
}

// ---------------- fused prep kernel ----------------
// kg-major layouts so main-kernel access is contiguous:
// x_p[mt 16][kg 64][m 128][8k] bf16 ; w_p[pair 100][kg 64][n' 128][8k] bf16 ;
// w_dt[t 200][32 node][64 n] bf16.
// Grid 3456: [0,256) prep_x | [256,1856) prep_wt | [1856,3456) prep_wd.
__global__ __launch_bounds__(256) void prep_all(
    const float* __restrict__ x, const float* __restrict__ w_t,
    const float* __restrict__ w_d,
    unsigned short* __restrict__ x_p, unsigned short* __restrict__ w_p,
    unsigned short* __restrict__ w_dt) {
    __shared__ float tile[64 * 65];
    int b = blockIdx.x;
    if (b < 256) {
        // ---- x [2048][512] f32 -> x_p ----
        int mb = b >> 3, slab = b & 7;
        const float* src = x + (mb * 64) * D_FEAT + slab * 64;
        #pragma unroll
        for (int p = 0; p < 16; ++p) {
            int idx = p * 256 + threadIdx.x;
            int r = idx >> 6, c = idx & 63;
            tile[r * 65 + c] = src[r * D_FEAT + c];
        }
        __syncthreads();
        int mt = mb >> 1, mq = mb & 1;
        unsigned short* dst = x_p + mt * 65536 + slab * 8192 + mq * 512;
        #pragma unroll
        for (int p = 0; p < 8; ++p) {
            int idx = p * 256 + threadIdx.x;
            int kgl = idx >> 8;
            int r   = (idx >> 2) & 63;
            int jp  = idx & 3;
            ushort2 o;
            o.x = f32_to_bf16(tile[r * 65 + kgl * 8 + jp * 2]);
            o.y = f32_to_bf16(tile[r * 65 + kgl * 8 + jp * 2 + 1]);
            *(ushort2*)(dst + kgl * 1024 + r * 8 + jp * 2) = o;
        }
    } else if (b < 1856) {
        // ---- w_t [t][d][n] f32 -> w_p (pair-interleaved, kg-major) ----
        int bb = b - 256;
        int t = bb >> 3, slab = bb & 7;
        const float* src = w_t + t * (D_FEAT * N_NODE) + slab * 64 * N_NODE;
        #pragma unroll
        for (int p = 0; p < 16; ++p) {
            int idx = p * 256 + threadIdx.x;
            int d = idx >> 6, n = idx & 63;
            tile[d * 65 + n] = src[d * N_NODE + n];
        }
        __syncthreads();
        unsigned short* dst = w_p + (t >> 1) * 65536 + slab * 8192 + (t & 1) * 512;
        #pragma unroll
        for (int p = 0; p < 8; ++p) {
            int idx = p * 256 + threadIdx.x;
            int kgl = idx >> 8;
            int n   = (idx >> 2) & 63;
            int jp  = idx & 3;
            ushort2 o;
            o.x = f32_to_bf16(tile[(kgl * 8 + jp * 2) * 65 + n]);
            o.y = f32_to_bf16(tile[(kgl * 8 + jp * 2 + 1) * 65 + n]);
            *(ushort2*)(dst + kgl * 1024 + n * 8 + jp * 2) = o;
        }
    } else {
        // ---- w_d [t][n][15] f32 -> w_dt [t][32][64] (rows 15..31 zero) ----
        int i = (b - 1856) * 256 + threadIdx.x;          // 409600 = 200*32*64
        int n = i & 63;
        int l = (i >> 6) & 31;
        int t = i >> 11;
        float v = (l < 15) ? w_d[(t * 64 + n) * 15 + l] : 0.f;
        w_dt[i] = f32_to_bf16(v);
    }
}

// ---------------- main fused kernel ----------------
// Block = 2 trees (N=128) x 128 batch rows, 256 threads (4 waves).
// Wave tile 64x64 (wm = w>>1 row-half, wn = w&1 = tree).
// A (x) fragments are loaded REGISTER-DIRECT from global (kg-major x_p: each
// lane's 16 B frag is contiguous; lanes 0..31 form a 512 B run; x_p is 2 MB,
// L2-resident per XCD). Ping-pong prefetch one full chunk ahead; the existing
// chunk barrier drains the loads. Only B goes through LDS (double-buffered
// 8 KB chunks) -> LDS traffic/chunk halves vs R7 (24 KB vs 48 KB), staging
// drain at the barrier halves too. __launch_bounds__(256,4): 4 blocks/CU
// (LDS 34.8 KB, regs ~115: acc 64 AGPR + a_cur/a_nxt 32 + bv 8 + addr).
__global__ __launch_bounds__(256, 4) void gbdt_main(
    const unsigned short* __restrict__ x_p,    // [16][64][128][8] bf16
    const unsigned short* __restrict__ w_p,    // [100][64][128][8] bf16
    const unsigned short* __restrict__ w_dt,   // [200][32][64] bf16
    const float* __restrict__ b_t,             // [200][64]
    const float* __restrict__ b_d,             // [200][15]
    const float* __restrict__ w_l,             // [200][16]
    const float* __restrict__ b_l,             // [200]
    float* __restrict__ f_ws)                  // [2048][200]  (b-major)
{
    // B dbuf: [0,16384) (8 KB per buffer). Overlays after GEMM1:
    // H [0,34816) = [2 tree][128 m][68 col] bf16 (136 B stride: 2-way bank
    // alias on GEMM2 frag reads = free); P [0,17408) = [2][128][17] f32.
    __shared__ alignas(16) char smem[34816];
    unsigned short* Hs = (unsigned short*)smem;
    float*          Pf = (float*)smem;

    const int tid    = threadIdx.x;
    const int lane   = tid & 63;
    const int w      = tid >> 6;
    const int lane31 = lane & 31;
    const int kh     = lane >> 5;
    const int wm     = w >> 1;       // row-half (0/1)
    const int wn     = w & 1;        // tree-in-pair (0/1)

    const int xcd  = blockIdx.x & 7;
    const int slot = blockIdx.x >> 3;     // 0..207
    const int mt   = slot & 15;           // 128-row tile
    const int pj   = slot >> 4;           // 0..12
    const int pair = xcd * 13 + pj;
    if (pair >= 100) return;
    const int t0 = pair * 2;
    const int m0 = mt * 128;

    // A frag base (elems): frag(c,s2,mb) at pA + c*4096 + s2*2048 + mb*256
    const unsigned short* pA = x_p + mt * 65536 + kh * 1024 + (wm * 64 + lane31) * 8;
    // B staging source (bytes): chunk stride 8192 B
    const char* gb = (const char*)(w_p + pair * 65536) + tid * 16;

    f32x16 acc[2][2];
    #pragma unroll
    for (int mb = 0; mb < 2; ++mb)
        #pragma unroll
        for (int nb = 0; nb < 2; ++nb)
            acc[mb][nb] = (f32x16)(0.f);

    // preload chunk-0 A frags (registers) and stage chunk-0 B (LDS buf 0)
    bf16x8 a_cur[4], a_nxt[4];
    #pragma unroll
    for (int s2 = 0; s2 < 2; ++s2)
        #pragma unroll
        for (int mb = 0; mb < 2; ++mb)
            a_cur[s2 * 2 + mb] = *(const bf16x8*)(pA + s2 * 2048 + mb * 256);
    gload_lds16(gb, smem + tid * 16);
    gload_lds16(gb + 4096, smem + tid * 16 + 4096);

    // ---- K loop: 16 chunks of 32, B double-buffered, A reg ping-pong ----
    for (int c = 0; c < 16; ++c) {
        __syncthreads();                             // drains B stage(c) + A(c) loads
        if (c < 15) {
            char* nx = smem + ((c + 1) & 1) * 8192;
            gload_lds16(gb + (c + 1) * 8192, nx + tid * 16);
            gload_lds16(gb + (c + 1) * 8192 + 4096, nx + tid * 16 + 4096);
            #pragma unroll
            for (int s2 = 0; s2 < 2; ++s2)
                #pragma unroll
                for (int mb = 0; mb < 2; ++mb)
                    a_nxt[s2 * 2 + mb] =
                        *(const bf16x8*)(pA + (c + 1) * 4096 + s2 * 2048 + mb * 256);
        }
        const char* buf = smem + (c & 1) * 8192;
        #pragma unroll
        for (int s2 = 0; s2 < 2; ++s2) {
            const int kgl = 2 * s2 + kh;
            bf16x8 bv[2];
            #pragma unroll
            for (int nb = 0; nb < 2; ++nb)
                bv[nb] = *(const bf16x8*)(buf + (kgl * 128 + wn * 64 + nb * 32 + lane31) * 16);
            #pragma unroll
            for (int mb = 0; mb < 2; ++mb)
                #pragma unroll
                for (int nb = 0; nb < 2; ++nb)
                    acc[mb][nb] = __builtin_amdgcn_mfma_f32_32x32x16_bf16(
                        a_cur[s2 * 2 + mb], bv[nb], acc[mb][nb], 0, 0, 0);
        }
        #pragma unroll
        for (int i = 0; i < 4; ++i) a_cur[i] = a_nxt[i];
    }

    __syncthreads();                                 // last B frag reads done

    // ---- epilogue: h = relu(acc + b_t) -> H LDS; acc dies here ----
    // C/D layout (32x32): col = lane&31, row = (r&3) + 8*(r>>2) + 4*(lane>>5)
    #pragma unroll
    for (int nb = 0; nb < 2; ++nb) {
        float btv = b_t[(t0 + wn) * 64 + nb * 32 + lane31];
        #pragma unroll
        for (int mb = 0; mb < 2; ++mb)
            #pragma unroll
            for (int r = 0; r < 16; ++r) {
                int m = wm * 64 + mb * 32 + (r & 3) + 8 * (r >> 2) + 4 * kh;
                float h = fmaxf(acc[mb][nb][r] + btv, 0.f);
                Hs[wn * 8704 + m * 68 + nb * 32 + lane31] = f32_to_bf16(h);
            }
    }
    __syncthreads();                                 // H complete for both trees

    // ---- GEMM2: wave (wm,wn): logit[64 m x 16 l] for tree wn, K=64 ----
    f32x16 acc2[2] = { (f32x16)(0.f), (f32x16)(0.f) };
    const unsigned short* pW = w_dt + (t0 + wn) * 2048 + lane31 * 64 + kh * 8;
    #pragma unroll
    for (int s = 0; s < 4; ++s) {
        bf16x8 bv = *(const bf16x8*)(pW + s * 16);
        #pragma unroll
        for (int i = 0; i < 2; ++i) {
            const unsigned short* pH =
                Hs + wn * 8704 + (wm * 64 + i * 32 + lane31) * 68 + s * 16 + kh * 8;
            bf16x8 av = *(const bf16x8*)pH;
            acc2[i] = __builtin_amdgcn_mfma_f32_32x32x16_bf16(av, bv, acc2[i], 0, 0, 0);
        }
    }
    __syncthreads();                                 // H reads done (P overlays H)

    // ---- p = sigmoid(logit + b_d) -> P [2][128][17] f32 ----
    if (lane31 < 15) {
        float bdv = b_d[(t0 + wn) * 15 + lane31];
        #pragma unroll
        for (int i = 0; i < 2; ++i)
            #pragma unroll
            for (int r = 0; r < 16; ++r) {
                int m = wm * 64 + i * 32 + (r & 3) + 8 * (r >> 2) + 4 * kh;
                float lg = acc2[i][r] + bdv;
                Pf[(wn * 128 + m) * 17 + lane31] = 1.f / (1.f + __expf(-lg));
            }
    }
    __syncthreads();

    // ---- soft routing + leaf score: thread = (tree j, row m) ----
    {
        int m = tid & 127;
        int j = tid >> 7;
        int t = t0 + j;
        float pv[15];
        #pragma unroll
        for (int i = 0; i < 15; ++i) pv[i] = Pf[(j * 128 + m) * 17 + i];
        float facc = 0.f;
        #pragma unroll
        for (int leaf = 0; leaf < 16; ++leaf) {
            float mu = 1.f;
            int node = 0;
            #pragma unroll
            for (int d = 0; d < 4; ++d) {
                int bit = (leaf >> (3 - d)) & 1;
                float p = pv[node];
                mu *= bit ? (1.f - p) : p;
                node = 2 * node + 1 + bit;
            }
            facc += mu * w_l[t * 16 + leaf];
        }
        f_ws[(m0 + m) * T_TREES + t] = tanhf(facc + b_l[t]);   // b-major
    }
}

// ---------------- boosting prefix-sum ----------------
// f_ws is [B][T] -> coalesced read.
__global__ void scan_k(const float* __restrict__ f_ws, const float* __restrict__ f0p,
                       float* __restrict__ out) {
    int b = blockIdx.x, tid = threadIdx.x;
    int lane = tid & 63, wid = tid >> 6;
    float f0 = f0p[0];
    float x = (tid < T_TREES) ? f_ws[b * T_TREES + tid] : 0.f;
    #pragma unroll
    for (int off = 1; off < 64; off <<= 1) {
        float y = __shfl_up(x, off, 64);
        if (lane >= off) x += y;
    }
    __shared__ float wsum[4];
    if (lane == 63) wsum[wid] = x;
    __syncthreads();
    float base = 0.f;
    for (int i = 0; i < wid; ++i) base += wsum[i];
    float incl = x + base;
    if (tid == 0) out[b * (T_TREES + 1)] = f0;
    if (tid < T_TREES) out[b * (T_TREES + 1) + 1 + tid] = f0 + LR * incl;
}

extern "C" void kernel_launch(void* const* d_in, const int* in_sizes, int n_in,
                              void* d_out, int out_size, void* d_ws, size_t ws_size,
                              hipStream_t stream) {
    const float* x   = (const float*)d_in[0];
    const float* w_t = (const float*)d_in[2];
    const float* b_t = (const float*)d_in[3];
    const float* w_d = (const float*)d_in[4];
    const float* b_d = (const float*)d_in[5];
    const float* w_l = (const float*)d_in[6];
    const float* b_l = (const float*)d_in[7];
    const float* f_0 = (const float*)d_in[8];
    float* out = (float*)d_out;

    char* ws = (char*)d_ws;
    unsigned short* x_p  = (unsigned short*)(ws);               // 2,097,152 B
    unsigned short* w_p  = (unsigned short*)(ws + 2097152);     // 13,107,200 B
    unsigned short* w_dt = (unsigned short*)(ws + 15204352);    //   819,200 B
    float*          f_ws = (float*)(ws + 16023552);             // 1,638,400 B

    prep_all<<<3456, 256, 0, stream>>>(x, w_t, w_d, x_p, w_p, w_dt);
    gbdt_main<<<1664, 256, 0, stream>>>(x_p, w_p, w_dt, b_t, b_d, w_l, b_l, f_ws);
    scan_k<<<BATCH, 256, 0, stream>>>(f_ws, f_0, out);
}